// Round 1
// baseline (10119.044 us; speedup 1.0000x reference)
//
#include <hip/hip_runtime.h>
#include <math.h>

// Problem constants
#define Lc 4
#define Hc 4
#define Bc 2
#define Tc 1024
#define Dc 1024
#define DFFc 4096
#define Vc 32000
#define BTc (Bc * Tc)

constexpr float EPSc = 1e-5f;
constexpr float SCALEc = 0.03125f; // 1/sqrt(1024)

// ---------------- reduction helpers (blockDim.x == 256 assumed) ----------------
__device__ __forceinline__ float block_reduce_max(float v) {
    #pragma unroll
    for (int o = 32; o > 0; o >>= 1) v = fmaxf(v, __shfl_down(v, o, 64));
    __shared__ float sm_[4];
    __syncthreads();
    if ((threadIdx.x & 63) == 0) sm_[threadIdx.x >> 6] = v;
    __syncthreads();
    return fmaxf(fmaxf(sm_[0], sm_[1]), fmaxf(sm_[2], sm_[3]));
}

__device__ __forceinline__ float block_reduce_sum(float v) {
    #pragma unroll
    for (int o = 32; o > 0; o >>= 1) v += __shfl_down(v, o, 64);
    __shared__ float ss_[4];
    __syncthreads();
    if ((threadIdx.x & 63) == 0) ss_[threadIdx.x >> 6] = v;
    __syncthreads();
    return ss_[0] + ss_[1] + ss_[2] + ss_[3];
}

// ---------------- embed: h = token_emb[x] + pos_embed ----------------
__global__ __launch_bounds__(256) void embed_kernel(const int* __restrict__ x,
                                                    const float* __restrict__ emb,
                                                    float* __restrict__ h) {
    long idx = (long)blockIdx.x * 256 + threadIdx.x; // < BT*D
    int d = (int)(idx & (Dc - 1));
    long bt = idx >> 10;
    int t = (int)(bt & (Tc - 1));
    int tok = x[bt];
    float denom = powf(10000.0f, (float)(2 * (d >> 1)) * (1.0f / Dc));
    float ang = (float)t / denom;
    float p = (d & 1) ? cosf(ang) : sinf(ang);
    h[idx] = emb[(long)tok * Dc + d] + p;
}

// ---------------- layernorm over D=1024, one block (256 thr) per row ----------------
__global__ __launch_bounds__(256) void layernorm_kernel(const float* __restrict__ X,
                                                        const float* __restrict__ g,
                                                        const float* __restrict__ b,
                                                        float* __restrict__ Y) {
    long row = blockIdx.x;
    float4 v = ((const float4*)(X + row * Dc))[threadIdx.x];
    float s  = v.x + v.y + v.z + v.w;
    float sq = v.x * v.x + v.y * v.y + v.z * v.z + v.w * v.w;
    #pragma unroll
    for (int o = 32; o > 0; o >>= 1) {
        s  += __shfl_down(s, o, 64);
        sq += __shfl_down(sq, o, 64);
    }
    __shared__ float ssum[4], ssq[4];
    if ((threadIdx.x & 63) == 0) { ssum[threadIdx.x >> 6] = s; ssq[threadIdx.x >> 6] = sq; }
    __syncthreads();
    s  = ssum[0] + ssum[1] + ssum[2] + ssum[3];
    sq = ssq[0] + ssq[1] + ssq[2] + ssq[3];
    float mu  = s * (1.0f / Dc);
    float var = sq * (1.0f / Dc) - mu * mu;
    float inv = rsqrtf(var + EPSc);
    float4 gv = ((const float4*)g)[threadIdx.x];
    float4 bv = ((const float4*)b)[threadIdx.x];
    float4 o;
    o.x = (v.x - mu) * inv * gv.x + bv.x;
    o.y = (v.y - mu) * inv * gv.y + bv.y;
    o.z = (v.z - mu) * inv * gv.z + bv.z;
    o.w = (v.w - mu) * inv * gv.w + bv.w;
    ((float4*)(Y + row * Dc))[threadIdx.x] = o;
}

// ---------------- causal softmax (applies scale; zeros masked cols) ----------------
__global__ __launch_bounds__(256) void softmax_causal_kernel(float* __restrict__ S) {
    int t = blockIdx.x;
    long z = blockIdx.y;
    float* row = S + (z * Tc + t) * (long)Tc;
    int n = t + 1;
    float m = -INFINITY;
    for (int s = threadIdx.x; s < n; s += 256) m = fmaxf(m, row[s] * SCALEc);
    m = block_reduce_max(m);
    float sum = 0.0f;
    for (int s = threadIdx.x; s < n; s += 256) sum += expf(row[s] * SCALEc - m);
    sum = block_reduce_sum(sum);
    float r = 1.0f / sum;
    for (int s = threadIdx.x; s < Tc; s += 256)
        row[s] = (s < n) ? expf(row[s] * SCALEc - m) * r : 0.0f;
}

// ---------------- in-place log_softmax over V=32000 ----------------
__global__ __launch_bounds__(256) void log_softmax_kernel(float* __restrict__ O) {
    float* x = O + (long)blockIdx.x * Vc;
    float m = -INFINITY;
    for (int i = threadIdx.x; i < Vc; i += 256) m = fmaxf(m, x[i]);
    m = block_reduce_max(m);
    float s = 0.0f;
    for (int i = threadIdx.x; i < Vc; i += 256) s += expf(x[i] - m);
    s = block_reduce_sum(s);
    float lse = m + logf(s);
    for (int i = threadIdx.x; i < Vc; i += 256) x[i] -= lse;
}

// ---------------- fp32 tiled GEMM: C = A[M,K] * B(K,N or N,K if TRANSB) (+bias)(+epilogue)
// EPI: 0 = store, 1 = C += (residual), 2 = gelu
// All of M,N divisible by 64; K divisible by 16. blockIdx.z batches with given strides.
template <bool TRANSB, int EPI>
__global__ __launch_bounds__(256) void gemm_kernel(
    const float* __restrict__ A, const float* __restrict__ Bm,
    const float* __restrict__ bias, float* __restrict__ C,
    int M, int N, int K, int lda, int ldb, int ldc,
    long sA, long sB, long sBias, long sC) {
    A  += (long)blockIdx.z * sA;
    Bm += (long)blockIdx.z * sB;
    C  += (long)blockIdx.z * sC;
    const float* bptr = bias ? (bias + (long)blockIdx.z * sBias) : nullptr;

    __shared__ __align__(16) float As[16][64];
    __shared__ __align__(16) float Bs[16][64];

    const int tid = threadIdx.x;
    const int tx = tid & 15, ty = tid >> 4;
    const int row0 = blockIdx.y * 64, col0 = blockIdx.x * 64;

    const int mA = tid >> 2, kA = (tid & 3) << 2; // A (and B^T) loads: 64 rows x 16 k
    const int kB = tid >> 4, nB = (tid & 15) << 2; // B NN loads: 16 k x 64 n

    float acc[4][4] = {{0.0f}};

    for (int k0 = 0; k0 < K; k0 += 16) {
        float4 a4 = *(const float4*)(A + (long)(row0 + mA) * lda + (k0 + kA));
        As[kA + 0][mA] = a4.x; As[kA + 1][mA] = a4.y;
        As[kA + 2][mA] = a4.z; As[kA + 3][mA] = a4.w;
        if (TRANSB) {
            float4 b4 = *(const float4*)(Bm + (long)(col0 + mA) * ldb + (k0 + kA));
            Bs[kA + 0][mA] = b4.x; Bs[kA + 1][mA] = b4.y;
            Bs[kA + 2][mA] = b4.z; Bs[kA + 3][mA] = b4.w;
        } else {
            *(float4*)&Bs[kB][nB] = *(const float4*)(Bm + (long)(k0 + kB) * ldb + (col0 + nB));
        }
        __syncthreads();
        #pragma unroll
        for (int k = 0; k < 16; ++k) {
            float4 av = *(const float4*)&As[k][ty << 2];
            float4 bv = *(const float4*)&Bs[k][tx << 2];
            float aa[4] = {av.x, av.y, av.z, av.w};
            float bb[4] = {bv.x, bv.y, bv.z, bv.w};
            #pragma unroll
            for (int i = 0; i < 4; ++i)
                #pragma unroll
                for (int j = 0; j < 4; ++j)
                    acc[i][j] = fmaf(aa[i], bb[j], acc[i][j]);
        }
        __syncthreads();
    }

    #pragma unroll
    for (int i = 0; i < 4; ++i) {
        long r = row0 + (ty << 2) + i;
        float* cp = C + r * (long)ldc + col0 + (tx << 2);
        float v[4];
        #pragma unroll
        for (int j = 0; j < 4; ++j)
            v[j] = acc[i][j] + (bptr ? bptr[col0 + (tx << 2) + j] : 0.0f);
        if (EPI == 1) {
            float4 c0 = *(const float4*)cp;
            v[0] += c0.x; v[1] += c0.y; v[2] += c0.z; v[3] += c0.w;
        } else if (EPI == 2) {
            #pragma unroll
            for (int j = 0; j < 4; ++j)
                v[j] = 0.5f * v[j] * (1.0f + erff(v[j] * 0.70710678118654752440f));
        }
        float4 o; o.x = v[0]; o.y = v[1]; o.z = v[2]; o.w = v[3];
        *(float4*)cp = o;
    }
}

// ---------------- orchestration ----------------
extern "C" void kernel_launch(void* const* d_in, const int* in_sizes, int n_in,
                              void* d_out, int out_size, void* d_ws, size_t ws_size,
                              hipStream_t stream) {
    (void)in_sizes; (void)n_in; (void)out_size; (void)ws_size;
    const int*   x    = (const int*)  d_in[0];
    const float* emb  = (const float*)d_in[1];
    const float* Wq   = (const float*)d_in[2];
    const float* bq   = (const float*)d_in[3];
    const float* Wk   = (const float*)d_in[4];
    const float* bk   = (const float*)d_in[5];
    const float* Wv   = (const float*)d_in[6];
    const float* bv   = (const float*)d_in[7];
    const float* Wo   = (const float*)d_in[8];
    const float* bo   = (const float*)d_in[9];
    const float* ln1g = (const float*)d_in[10];
    const float* ln1b = (const float*)d_in[11];
    const float* ln2g = (const float*)d_in[12];
    const float* ln2b = (const float*)d_in[13];
    const float* W1   = (const float*)d_in[14];
    const float* b1   = (const float*)d_in[15];
    const float* W2   = (const float*)d_in[16];
    const float* b2   = (const float*)d_in[17];
    const float* flng = (const float*)d_in[18];
    const float* flnb = (const float*)d_in[19];
    const float* Wout = (const float*)d_in[20];
    float* out = (float*)d_out;

    // workspace layout (floats): h | xn | Q[H,B,T,D] | K[H,B,T,D] | V[H,B,T,D] | S[B*H,T,T]
    // aliases: y2 (attn out, [H,B,T,D]) <- K buffer ; mff ([BT,DFF]) <- Q buffer
    float* h   = (float*)d_ws;
    float* xn  = h  + (long)BTc * Dc;
    float* Qb  = xn + (long)BTc * Dc;
    float* Kb  = Qb + (long)Hc * BTc * Dc;
    float* Vb  = Kb + (long)Hc * BTc * Dc;
    float* Sb  = Vb + (long)Hc * BTc * Dc;
    float* y2  = Kb;
    float* mff = Qb;

    embed_kernel<<<(BTc * Dc) / 256, 256, 0, stream>>>(x, emb, h);

    for (int l = 0; l < Lc; ++l) {
        layernorm_kernel<<<BTc, 256, 0, stream>>>(h, ln1g + l * Dc, ln1b + l * Dc, xn);

        // QKV projections, z batches heads; output layout [H, B*T, D] (z = h*B + b on T*D slices)
        dim3 gqkv(Dc / 64, BTc / 64, Hc);
        gemm_kernel<false, 0><<<gqkv, 256, 0, stream>>>(
            xn, Wq + (long)l * Hc * Dc * Dc, bq + (long)l * Hc * Dc, Qb,
            BTc, Dc, Dc, Dc, Dc, Dc, 0L, (long)Dc * Dc, (long)Dc, (long)BTc * Dc);
        gemm_kernel<false, 0><<<gqkv, 256, 0, stream>>>(
            xn, Wk + (long)l * Hc * Dc * Dc, bk + (long)l * Hc * Dc, Kb,
            BTc, Dc, Dc, Dc, Dc, Dc, 0L, (long)Dc * Dc, (long)Dc, (long)BTc * Dc);
        gemm_kernel<false, 0><<<gqkv, 256, 0, stream>>>(
            xn, Wv + (long)l * Hc * Dc * Dc, bv + (long)l * Hc * Dc, Vb,
            BTc, Dc, Dc, Dc, Dc, Dc, 0L, (long)Dc * Dc, (long)Dc, (long)BTc * Dc);

        // S = Q @ K^T per (h,b): z = h*B+b, slices of T*D / output T*T
        dim3 gs(Tc / 64, Tc / 64, Bc * Hc);
        gemm_kernel<true, 0><<<gs, 256, 0, stream>>>(
            Qb, Kb, nullptr, Sb,
            Tc, Tc, Dc, Dc, Dc, Tc, (long)Tc * Dc, (long)Tc * Dc, 0L, (long)Tc * Tc);

        softmax_causal_kernel<<<dim3(Tc, Bc * Hc), 256, 0, stream>>>(Sb);

        // y2 = A @ V  (writes into K buffer; K no longer needed)
        dim3 gav(Dc / 64, Tc / 64, Bc * Hc);
        gemm_kernel<false, 0><<<gav, 256, 0, stream>>>(
            Sb, Vb, nullptr, y2,
            Tc, Dc, Tc, Tc, Dc, Dc, (long)Tc * Tc, (long)Tc * Dc, 0L, (long)Tc * Dc);

        // h += y @ Wo + bo, decomposed over heads (K-split, sequential accumulate)
        for (int hh = 0; hh < Hc; ++hh) {
            gemm_kernel<false, 1><<<dim3(Dc / 64, BTc / 64), 256, 0, stream>>>(
                y2 + (long)hh * BTc * Dc, Wo + ((long)l * Hc + hh) * Dc * Dc,
                hh == 0 ? bo + (long)l * Dc : nullptr, h,
                BTc, Dc, Dc, Dc, Dc, Dc, 0L, 0L, 0L, 0L);
        }

        // MLP
        layernorm_kernel<<<BTc, 256, 0, stream>>>(h, ln2g + l * Dc, ln2b + l * Dc, xn);
        gemm_kernel<false, 2><<<dim3(DFFc / 64, BTc / 64), 256, 0, stream>>>(
            xn, W1 + (long)l * Dc * DFFc, b1 + (long)l * DFFc, mff,
            BTc, DFFc, Dc, Dc, DFFc, DFFc, 0L, 0L, 0L, 0L);
        gemm_kernel<false, 1><<<dim3(Dc / 64, BTc / 64), 256, 0, stream>>>(
            mff, W2 + (long)l * DFFc * Dc, b2 + (long)l * Dc, h,
            BTc, Dc, DFFc, DFFc, Dc, Dc, 0L, 0L, 0L, 0L);
    }

    layernorm_kernel<<<BTc, 256, 0, stream>>>(h, flng, flnb, xn);
    gemm_kernel<false, 0><<<dim3(Vc / 64, BTc / 64), 256, 0, stream>>>(
        xn, Wout, nullptr, out, BTc, Vc, Dc, Dc, Vc, Vc, 0L, 0L, 0L, 0L);
    log_softmax_kernel<<<BTc, 256, 0, stream>>>(out);
}